// Round 12
// baseline (796.992 us; speedup 1.0000x reference)
//
#include <hip/hip_runtime.h>
#include <climits>

// Problem constants (fixed by reference setup_inputs)
constexpr int N_NODES = 50000;
constexpr int N_EDGES = 800000;
constexpr int DIM     = 128;
constexpr int DIM4    = DIM / 4;          // 32 float4 columns
constexpr float BN_EPS = 1e-5f;

constexpr int EMPTY = 0x7F7F7F7F;         // > any edge index; min-stable sentinel

// Two-stage select: 16 node chunks x 16 edge chunks, 1024-thread scan blocks.
constexpr int NC = 16;
constexpr int EC = 16;
constexpr int NODES_PER_NC = N_NODES / NC;      // 3125 (50 KB LDS table)
constexpr int EDGES_PER_EC = N_EDGES / EC;      // 50000
constexpr int E4_PER_EC    = EDGES_PER_EC / 4;  // 12500 int4 loads per chunk
constexpr int SEL_THREADS  = 1024;

// Fused conv+bn kernel: MUST be fully co-resident for the spin barrier.
// 1250 blocks, __launch_bounds__(256,5) -> <=102 VGPR -> >=5 blocks/CU
// -> capacity 1280 blocks >= 1250. LDS ~3 KB, 20 waves/CU: no other limit.
constexpr int F_NODES_PER_ITER = 8;       // 256 threads / 32 float4-cols
constexpr int F_ITERS          = 5;
constexpr int F_NPB            = F_NODES_PER_ITER * F_ITERS;   // 40
constexpr int F_GRID           = N_NODES / F_NPB;              // 1250 exactly

constexpr int NBUCKETS = 64;              // stats atomic spreading
constexpr int NB_MERGE = (N_NODES + 255) / 256;   // 196 merge blocks in stage B

// ---------------- float4 helpers ----------------
__device__ inline float4 f4min(float4 a, float4 b) {
    return make_float4(fminf(a.x,b.x), fminf(a.y,b.y), fminf(a.z,b.z), fminf(a.w,b.w));
}
__device__ inline float4 f4max(float4 a, float4 b) {
    return make_float4(fmaxf(a.x,b.x), fmaxf(a.y,b.y), fmaxf(a.z,b.z), fmaxf(a.w,b.w));
}
__device__ inline float4 f4add(float4 a, float4 b) {
    return make_float4(a.x+b.x, a.y+b.y, a.z+b.z, a.w+b.w);
}
__device__ inline float4 f4fma(float s, float4 v, float4 acc) {   // acc + s*v
    return make_float4(fmaf(s,v.x,acc.x), fmaf(s,v.y,acc.y), fmaf(s,v.z,acc.z), fmaf(s,v.w,acc.w));
}

// ---------------------------------------------------------------------------
// Select stage A: block (nc, ec) scans edge chunk ec with 1024 threads,
// inserts edges whose dst lies in node chunk nc into an LDS top-4 table
// (cascaded LDS atomicMin = concurrent sorted insert), then streams the
// table to tables[ec][node] with plain coalesced stores (one writer/cell).
// ---------------------------------------------------------------------------
__global__ __launch_bounds__(SEL_THREADS)
void select_stageA_kernel(const int* __restrict__ dst,
                          int* __restrict__ tables) {
    __shared__ int slot[NODES_PER_NC * 4];    // 50 KB
    const int nc = blockIdx.x & (NC - 1);
    const int ec = blockIdx.x >> 4;
    const int t  = threadIdx.x;

    for (int i = t; i < NODES_PER_NC * 4; i += SEL_THREADS) slot[i] = EMPTY;
    __syncthreads();

    const int r0 = nc * NODES_PER_NC;
    const int4* __restrict__ dst4 = (const int4*)dst;
    const int base4 = ec * E4_PER_EC;
    for (int i = t; i < E4_PER_EC; i += SEL_THREADS) {
        const int4 d = dst4[base4 + i];
        const int ebase = 4 * (base4 + i);
        #define TRY_INS(comp, off) {                                        \
            unsigned n_ = (unsigned)((comp) - r0);                          \
            if (n_ < (unsigned)NODES_PER_NC) {                              \
                int cur_ = ebase + (off);                                   \
                _Pragma("unroll")                                           \
                for (int j_ = 0; j_ < 4; ++j_) {                            \
                    int old_ = atomicMin(&slot[4 * n_ + j_], cur_);         \
                    if (old_ == EMPTY) break;                               \
                    cur_ = max(cur_, old_);                                 \
                } } }
        TRY_INS(d.x, 0); TRY_INS(d.y, 1); TRY_INS(d.z, 2); TRY_INS(d.w, 3);
        #undef TRY_INS
    }
    __syncthreads();

    int4* __restrict__ out = (int4*)tables + (size_t)ec * N_NODES + r0;
    const int4* __restrict__ sl4 = (const int4*)slot;
    for (int n = t; n < NODES_PER_NC; n += SEL_THREADS) out[n] = sl4[n];
}

// ---------------------------------------------------------------------------
// Select stage B + housekeeping. Blocks [0, NB_MERGE): per node, merge the 16
// per-chunk sorted top-4 lists into the global top-4 (exact), map through src
// (-1 = empty); also zero stats_part and the barrier counters. Blocks
// NB_MERGE / NB_MERGE+1: blank_p[l] = W_l @ blank_l + b_l.
// ---------------------------------------------------------------------------
__global__ __launch_bounds__(256)
void select_stageB_kernel(const int* __restrict__ tables,
                          const int* __restrict__ src,
                          int4* __restrict__ srcs4,
                          float* __restrict__ stats_part,   // zeroed here
                          int* __restrict__ counters,       // zeroed here (2)
                          const float* __restrict__ W0, const float* __restrict__ b0,
                          const float* __restrict__ bl0,
                          const float* __restrict__ W1, const float* __restrict__ b1,
                          const float* __restrict__ bl1,
                          float* __restrict__ bp) {
    const int t = threadIdx.x;

    if (blockIdx.x >= NB_MERGE) {         // blank-projection blocks
        int l = blockIdx.x - NB_MERGE;
        if (t < DIM) {
            const float* W  = l ? W1  : W0;
            const float* b  = l ? b1  : b0;
            const float* bl = l ? bl1 : bl0;
            float s = 0.f;
            #pragma unroll 8
            for (int j = 0; j < DIM; ++j) s += W[t * DIM + j] * bl[j];
            bp[l * DIM + t] = s + b[t];
        }
        if (t == 200) counters[l] = 0;    // reset barrier counter for layer l
        return;
    }

    const int gid = blockIdx.x * 256 + t;
    if (gid < 2 * NBUCKETS * 256) stats_part[gid] = 0.f;   // fold the memset

    const int v = gid;
    if (v >= N_NODES) return;

    int b0_ = EMPTY, b1_ = EMPTY, b2_ = EMPTY, b3_ = EMPTY;
    #pragma unroll
    for (int ec = 0; ec < EC; ++ec) {
        const int4 c = ((const int4*)tables)[(size_t)ec * N_NODES + v];
        if (c.x >= b3_) continue;         // chunk min can't improve top-4
        #define INS(val) {                                          \
            int x_ = (val);                                         \
            if (x_ < b3_) { b3_ = x_;                               \
                int tm;                                             \
                if (b3_ < b2_) { tm = b2_; b2_ = b3_; b3_ = tm; }   \
                if (b2_ < b1_) { tm = b1_; b1_ = b2_; b2_ = tm; }   \
                if (b1_ < b0_) { tm = b0_; b0_ = b1_; b1_ = tm; } } }
        INS(c.x); INS(c.y); INS(c.z); INS(c.w);
        #undef INS
    }
    int4 o;
    o.x = (b0_ < N_EDGES) ? src[b0_] : -1;
    o.y = (b1_ < N_EDGES) ? src[b1_] : -1;
    o.z = (b2_ < N_EDGES) ? src[b2_] : -1;
    o.w = (b3_ < N_EDGES) ? src[b3_] : -1;
    srcs4[v] = o;
}

// ---------------------------------------------------------------------------
// Fully fused sort-conv + BN stats + BN apply. h and xin stay in registers
// across a hand-rolled grid barrier (arrive-and-spin on a device counter;
// co-residency guaranteed: 1250 blocks <= 1280 resident slots from
// __launch_bounds__(256,5)). After the barrier every block folds the 64
// stat buckets itself (L2-hot broadcast) -- no second barrier needed.
// ---------------------------------------------------------------------------
__global__ __launch_bounds__(256, 5)
void fused_conv_bn_kernel(const float* __restrict__ x,
                          const int4* __restrict__ srcs4,
                          const float* __restrict__ bp,      // 128 floats (layer)
                          const float* __restrict__ cw,
                          const float* __restrict__ cb,
                          const float* __restrict__ a,
                          const float* __restrict__ g,
                          const float* __restrict__ be,
                          float* __restrict__ stats_part,    // [NBUCKETS][256]
                          int* __restrict__ counter,         // barrier counter
                          float* __restrict__ xout) {
    const int t    = threadIdx.x;
    const int d4   = t & (DIM4 - 1);
    const int nsub = t >> 5;

    const float4* __restrict__ x4 = (const float4*)x;

    const float aa = a[0];
    const float c0 = cw[0], c1 = cw[1], c2 = cw[2], c3 = cw[3];
    const float cbv = cb[0];
    const float4 bpv = ((const float4*)bp)[d4];

    float4 s  = make_float4(0.f, 0.f, 0.f, 0.f);
    float4 s2 = make_float4(0.f, 0.f, 0.f, 0.f);
    float4 hreg[F_ITERS];
    float4 xreg[F_ITERS];

    const int vbase = blockIdx.x * F_NPB;
    #pragma unroll
    for (int it = 0; it < F_ITERS; ++it) {
        const int v = vbase + it * F_NODES_PER_ITER + nsub;   // always < N_NODES
        const int4 sv = srcs4[v];
        float4 m0 = (sv.x >= 0) ? x4[(size_t)max(sv.x,0) * DIM4 + d4] : bpv;
        float4 m1 = (sv.y >= 0) ? x4[(size_t)max(sv.y,0) * DIM4 + d4] : bpv;
        float4 m2 = (sv.z >= 0) ? x4[(size_t)max(sv.z,0) * DIM4 + d4] : bpv;
        float4 m3 = (sv.w >= 0) ? x4[(size_t)max(sv.w,0) * DIM4 + d4] : bpv;

        // component-wise 4-element sorting network (0,1)(2,3)(0,2)(1,3)(1,2)
        #define CSWAP4(p, q) { float4 lo = f4min(p, q); float4 hi = f4max(p, q); p = lo; q = hi; }
        CSWAP4(m0, m1); CSWAP4(m2, m3); CSWAP4(m0, m2); CSWAP4(m1, m3); CSWAP4(m1, m2);
        #undef CSWAP4

        float4 xv = x4[(size_t)v * DIM4 + d4];
        float4 hv = make_float4(cbv, cbv, cbv, cbv);
        hv = f4fma(c0, m0, hv);
        hv = f4fma(c1, m1, hv);
        hv = f4fma(c2, m2, hv);
        hv = f4fma(c3, m3, hv);
        hv = f4fma(aa, xv, hv);
        hreg[it] = hv;
        xreg[it] = xv;

        s  = f4add(s, hv);
        s2 = f4add(s2, make_float4(hv.x*hv.x, hv.y*hv.y, hv.z*hv.z, hv.w*hv.w));
    }

    // intra-wave: lane i += lane i+32 (same d4 column, different node)
    s.x  += __shfl_down(s.x, 32);  s.y  += __shfl_down(s.y, 32);
    s.z  += __shfl_down(s.z, 32);  s.w  += __shfl_down(s.w, 32);
    s2.x += __shfl_down(s2.x, 32); s2.y += __shfl_down(s2.y, 32);
    s2.z += __shfl_down(s2.z, 32); s2.w += __shfl_down(s2.w, 32);

    __shared__ float4 ls[4][32];
    __shared__ float4 ls2[4][32];
    const int wave = t >> 6;
    const int lane = t & 63;
    if (lane < 32) { ls[wave][lane] = s; ls2[wave][lane] = s2; }
    __syncthreads();
    if (t < 32) {
        float* bucket = stats_part + (size_t)(blockIdx.x & (NBUCKETS - 1)) * 256;
        float4 fs  = f4add(f4add(ls[0][t],  ls[1][t]),  f4add(ls[2][t],  ls[3][t]));
        float4 fs2 = f4add(f4add(ls2[0][t], ls2[1][t]), f4add(ls2[2][t], ls2[3][t]));
        atomicAdd(&bucket[4*t + 0], fs.x);
        atomicAdd(&bucket[4*t + 1], fs.y);
        atomicAdd(&bucket[4*t + 2], fs.z);
        atomicAdd(&bucket[4*t + 3], fs.w);
        atomicAdd(&bucket[DIM + 4*t + 0], fs2.x);
        atomicAdd(&bucket[DIM + 4*t + 1], fs2.y);
        atomicAdd(&bucket[DIM + 4*t + 2], fs2.z);
        atomicAdd(&bucket[DIM + 4*t + 3], fs2.w);
    }

    // ---- hand-rolled grid barrier (all blocks co-resident by construction) ----
    __threadfence();                      // make bucket adds device-visible
    if (t == 0) {
        __hip_atomic_fetch_add(counter, 1, __ATOMIC_ACQ_REL, __HIP_MEMORY_SCOPE_AGENT);
        while (__hip_atomic_load(counter, __ATOMIC_ACQUIRE, __HIP_MEMORY_SCOPE_AGENT)
               < F_GRID)
            __builtin_amdgcn_s_sleep(8);
    }
    __syncthreads();

    // every block folds the 64 buckets (L2-hot broadcast reads)
    __shared__ float red[256];
    {
        float acc = 0.f;
        #pragma unroll 8
        for (int k = 0; k < NBUCKETS; ++k)
            acc += __hip_atomic_load(&stats_part[k * 256 + t],
                                     __ATOMIC_RELAXED, __HIP_MEMORY_SCOPE_AGENT);
        red[t] = acc;
    }
    __syncthreads();

    constexpr float invN = 1.0f / (float)N_NODES;
    float4 mu, iv;
    {
        float m0_ = red[4*d4 + 0] * invN, m1_ = red[4*d4 + 1] * invN;
        float m2_ = red[4*d4 + 2] * invN, m3_ = red[4*d4 + 3] * invN;
        mu = make_float4(m0_, m1_, m2_, m3_);
        iv.x = rsqrtf(red[DIM + 4*d4 + 0] * invN - m0_*m0_ + BN_EPS);
        iv.y = rsqrtf(red[DIM + 4*d4 + 1] * invN - m1_*m1_ + BN_EPS);
        iv.z = rsqrtf(red[DIM + 4*d4 + 2] * invN - m2_*m2_ + BN_EPS);
        iv.w = rsqrtf(red[DIM + 4*d4 + 3] * invN - m3_*m3_ + BN_EPS);
    }
    const float4 gv = ((const float4*)g)[d4];
    const float4 bv = ((const float4*)be)[d4];

    float4* __restrict__ o4 = (float4*)xout;
    #pragma unroll
    for (int it = 0; it < F_ITERS; ++it) {
        const int v = vbase + it * F_NODES_PER_ITER + nsub;
        float4 hv = hreg[it], xv = xreg[it], o;
        o.x = xv.x + (hv.x - mu.x) * iv.x * gv.x + bv.x;
        o.y = xv.y + (hv.y - mu.y) * iv.y * gv.y + bv.y;
        o.z = xv.z + (hv.z - mu.z) * iv.z * gv.z + bv.z;
        o.w = xv.w + (hv.w - mu.w) * iv.w * gv.w + bv.w;
        o4[(size_t)v * DIM4 + d4] = o;
    }
}

extern "C" void kernel_launch(void* const* d_in, const int* in_sizes, int n_in,
                              void* d_out, int out_size, void* d_ws, size_t ws_size,
                              hipStream_t stream) {
    const float* x0  = (const float*)d_in[0];
    const int*   ei  = (const int*)d_in[1];
    const int*   src = ei;               // edge_index[0]
    const int*   dst = ei + N_EDGES;     // edge_index[1]

    const float* W[2]; const float* b[2]; const float* cw[2]; const float* cb[2];
    const float* a[2]; const float* g[2]; const float* be[2]; const float* blank[2];
    for (int i = 0; i < 2; ++i) {
        int o = 2 + 8 * i;
        W[i]     = (const float*)d_in[o + 0];
        b[i]     = (const float*)d_in[o + 1];
        cw[i]    = (const float*)d_in[o + 2];
        cb[i]    = (const float*)d_in[o + 3];
        a[i]     = (const float*)d_in[o + 4];
        g[i]     = (const float*)d_in[o + 5];
        be[i]    = (const float*)d_in[o + 6];
        blank[i] = (const float*)d_in[o + 7];
    }

    // Workspace layout (re-poisoned 0xAA each call — init everything used).
    char* ws = (char*)d_ws;
    int*   srcs       = (int*)ws;                                 // 4N ints, int4/node
    int*   tables     = srcs + 4 * N_NODES;                       // 16*4N ints = 12.8 MB
    float* stats_part = (float*)(tables + (size_t)EC * 4 * N_NODES); // 2*64*256 floats
    float* bp         = stats_part + 2 * NBUCKETS * 256;          // 256 floats (2 layers)
    int*   counters   = (int*)(bp + 256);                         // 2 barrier counters

    float* xout = (float*)d_out;

    // ---- two-stage selection + housekeeping ----
    select_stageA_kernel<<<NC * EC, SEL_THREADS, 0, stream>>>(dst, tables);
    select_stageB_kernel<<<NB_MERGE + 2, 256, 0, stream>>>(
        tables, src, (int4*)srcs, stats_part, counters,
        W[0], b[0], blank[0], W[1], b[1], blank[1], bp);

    // ---- two fused conv+bn layers ----
    for (int l = 0; l < 2; ++l) {
        const float* xin = (l == 0) ? x0 : xout;
        float* sp = stats_part + (size_t)l * NBUCKETS * 256;
        fused_conv_bn_kernel<<<F_GRID, 256, 0, stream>>>(
            xin, (const int4*)srcs, bp + l * DIM, cw[l], cb[l], a[l],
            g[l], be[l], sp, counters + l, xout);
    }
}